// Round 10
// baseline (14443.539 us; speedup 1.0000x reference)
//
#include <hip/hip_runtime.h>
#include <hip/hip_bf16.h>

typedef __hip_bfloat16 bf16;
typedef unsigned short u16;

#define R_RECON 3145728
#define N_IDX   65536

// dual-dtype input load: fl=1 -> fp32 (expected), fl=0 -> bf16
__device__ __forceinline__ float ldg_in(const void* p, int i, int fl) {
  return fl ? ((const float*)p)[i] : __bfloat162float(((const bf16*)p)[i]);
}

// fp32 misread as bf16 shows |v|>16384/NaN among low-half words over 4096 samples.
__global__ __launch_bounds__(256) void k_detect(const u16* __restrict__ p, int* __restrict__ flag) {
  __shared__ int s;
  if (threadIdx.x == 0) s = 0;
  __syncthreads();
  for (int i = threadIdx.x; i < 4096; i += 256) {
    float f = __uint_as_float(((unsigned)p[i]) << 16);
    if (!(fabsf(f) < 16384.f)) atomicOr(&s, 1);
  }
  __syncthreads();
  if (threadIdx.x == 0) flag[0] = s;
}

// ---------------- stride-2 4x4 conv, pad 1, out = relu(conv + bias) ----------------
template<bool GIN>
__global__ __launch_bounds__(256) void k_conv_s2k4(
    const void* __restrict__ inp, const void* __restrict__ w,
    const void* __restrict__ bias, float* __restrict__ out,
    const int* __restrict__ flag, int in_off,
    int Cin, int Hin, int Cout, int Hout)
{
  __shared__ float sW[1024];           // Cin*16 <= 1024
  int fl = flag[0];
  int tid = threadIdx.x;
  int idx = blockIdx.x * 256 + tid;
  int hw = Hout * Hout;
  int co = (idx / hw) % Cout;          // uniform (256 divides hw)
  for (int i = tid; i < Cin * 16; i += 256)
    sW[i] = ldg_in(w, co * Cin * 16 + i, fl);
  __syncthreads();
  int ox = idx % Hout; int t = idx / Hout;
  int oy = t % Hout;
  int n = idx / (hw * Cout);
  float acc = ldg_in(bias, co, fl);
  int iy0 = 2 * oy - 1, ix0 = 2 * ox - 1;
  const float* inf = (const float*)inp;
  for (int ci = 0; ci < Cin; ++ci) {
    int base_in = (n * Cin + ci) * Hin * Hin;
    const float* wp = sW + ci * 16;
    #pragma unroll
    for (int ky = 0; ky < 4; ++ky) {
      int iy = iy0 + ky;
      if ((unsigned)iy >= (unsigned)Hin) continue;
      int rb = base_in + iy * Hin;
      #pragma unroll
      for (int kx = 0; kx < 4; ++kx) {
        int ix = ix0 + kx;
        if ((unsigned)ix >= (unsigned)Hin) continue;
        float v = GIN ? ldg_in(inp, in_off + rb + ix, fl) : inf[rb + ix];
        acc = fmaf(v, wp[ky * 4 + kx], acc);
      }
    }
  }
  out[idx] = fmaxf(acc, 0.f);
}

// ---------------- 3x3 conv, stride 1, pad 1, H=W=32 ----------------
// TRANS_W: torch ConvTranspose layout (I,O,3,3); flip applied at staging.
template<bool IN_RELU, bool TRANS_W, bool OUT_RELU, bool HAS_BIAS>
__global__ __launch_bounds__(256) void k_conv3x3(
    const float* __restrict__ in, const void* __restrict__ w,
    const void* __restrict__ bias, float* __restrict__ out,
    const int* __restrict__ flag, int Cin, int Cout)
{
  const int H = 32, HW = 1024;
  __shared__ float sW[1152];           // Cin*9 <= 1152
  int fl = flag[0];
  int bc = blockIdx.x;
  int co = bc % Cout, n = bc / Cout;
  int tid = threadIdx.x;
  for (int i = tid; i < Cin * 9; i += 256) {
    int src = TRANS_W ? ((i / 9) * Cout + co) * 9 + (8 - (i % 9))
                      : (co * Cin + (i / 9)) * 9 + (i % 9);
    sW[i] = ldg_in(w, src, fl);
  }
  __syncthreads();
  int oy = tid >> 3;
  int ox0 = (tid & 7) << 2;
  float bv = HAS_BIAS ? ldg_in(bias, co, fl) : 0.f;
  float acc0 = bv, acc1 = bv, acc2 = bv, acc3 = bv;
  for (int ci = 0; ci < Cin; ++ci) {
    const float* ip = in + (n * Cin + ci) * HW;
    #pragma unroll
    for (int ky = 0; ky < 3; ++ky) {
      int iy = oy - 1 + ky;
      if ((unsigned)iy < (unsigned)H) {
        const float* rp = ip + iy * H;
        float x0, x1, x2, x3, x4, x5;
        {
          int ix;
          ix = ox0 - 1; x0 = ((unsigned)ix < (unsigned)H) ? rp[ix] : 0.f;
          x1 = rp[ox0 + 0]; x2 = rp[ox0 + 1]; x3 = rp[ox0 + 2]; x4 = rp[ox0 + 3];
          ix = ox0 + 4; x5 = ((unsigned)ix < (unsigned)H) ? rp[ix] : 0.f;
        }
        if (IN_RELU) {
          x0 = fmaxf(x0, 0.f); x1 = fmaxf(x1, 0.f); x2 = fmaxf(x2, 0.f);
          x3 = fmaxf(x3, 0.f); x4 = fmaxf(x4, 0.f); x5 = fmaxf(x5, 0.f);
        }
        const float* q = sW + ci * 9 + ky * 3;
        float w0 = q[0], w1 = q[1], w2 = q[2];
        acc0 = fmaf(x0, w0, fmaf(x1, w1, fmaf(x2, w2, acc0)));
        acc1 = fmaf(x1, w0, fmaf(x2, w1, fmaf(x3, w2, acc1)));
        acc2 = fmaf(x2, w0, fmaf(x3, w1, fmaf(x4, w2, acc2)));
        acc3 = fmaf(x3, w0, fmaf(x4, w1, fmaf(x5, w2, acc3)));
      }
    }
  }
  if (OUT_RELU) {
    acc0 = fmaxf(acc0, 0.f); acc1 = fmaxf(acc1, 0.f);
    acc2 = fmaxf(acc2, 0.f); acc3 = fmaxf(acc3, 0.f);
  }
  float* op = out + (n * Cout + co) * HW + oy * H + ox0;
  op[0] = acc0; op[1] = acc1; op[2] = acc2; op[3] = acc3;
}

// ---------------- 1x1 conv over 32x32 ----------------
template<bool IN_RELU, bool ACCUM, bool HAS_BIAS>
__global__ __launch_bounds__(256) void k_conv1x1(
    const float* __restrict__ in, const void* __restrict__ w,
    const void* __restrict__ bias, float* __restrict__ out,
    const int* __restrict__ flag, int Cin, int Cout)
{
  const int HW = 1024;
  __shared__ float sW[128];
  int fl = flag[0];
  int idx = blockIdx.x * 256 + threadIdx.x;
  int p = idx & (HW - 1); int t = idx >> 10;
  int co = t % Cout; int n = t / Cout;
  for (int i = threadIdx.x; i < Cin; i += 256)
    sW[i] = ldg_in(w, co * Cin + i, fl);
  __syncthreads();
  float acc = HAS_BIAS ? ldg_in(bias, co, fl) : 0.f;
  const float* ip = in + n * Cin * HW + p;
  for (int ci = 0; ci < Cin; ++ci) {
    float v = ip[ci * HW];
    if (IN_RELU) v = fmaxf(v, 0.f);
    acc = fmaf(v, sW[ci], acc);
  }
  if (ACCUM) out[idx] += acc; else out[idx] = acc;
}

// ---------------- ConvTranspose stride 2, k=4, pad 1 (gather form) ----------------
// y[n,o,oy,ox] = b[o] + sum_{ci,ky,kx valid} in[n,ci,(oy+1-ky)/2,(ox+1-kx)/2] * w[ci,o,ky,kx]
template<bool IN_RELU, bool OUT_RELU>
__global__ __launch_bounds__(256) void k_convT_s2k4(
    const float* __restrict__ in, const void* __restrict__ w,
    const void* __restrict__ bias, float* __restrict__ out,
    const int* __restrict__ flag, int Cin, int Hin, int Cout)
{
  __shared__ float sW[2048];           // Cin*16 <= 2048
  int fl = flag[0];
  int Hout = Hin * 2;
  int tid = threadIdx.x;
  int idx = blockIdx.x * 256 + tid;
  int hw = Hout * Hout;
  int co = (idx / hw) % Cout;          // uniform (256 divides hw)
  for (int i = tid; i < Cin * 16; i += 256)
    sW[i] = ldg_in(w, ((i >> 4) * Cout + co) * 16 + (i & 15), fl);
  __syncthreads();
  int ox = idx % Hout; int t = idx / Hout;
  int oy = t % Hout;
  int n = idx / (hw * Cout);
  float acc = ldg_in(bias, co, fl);
  int iy[4], ix[4];
  bool vy[4], vx[4];
  #pragma unroll
  for (int k = 0; k < 4; ++k) {
    int ty = oy + 1 - k;
    vy[k] = (ty >= 0) && ((ty & 1) == 0) && ((ty >> 1) < Hin);
    iy[k] = ty >> 1;
    int tx = ox + 1 - k;
    vx[k] = (tx >= 0) && ((tx & 1) == 0) && ((tx >> 1) < Hin);
    ix[k] = tx >> 1;
  }
  for (int ci = 0; ci < Cin; ++ci) {
    const float* ip = in + (n * Cin + ci) * Hin * Hin;
    const float* wp = sW + ci * 16;
    #pragma unroll
    for (int ky = 0; ky < 4; ++ky) {
      if (!vy[ky]) continue;
      const float* rp = ip + iy[ky] * Hin;
      #pragma unroll
      for (int kx = 0; kx < 4; ++kx) {
        if (!vx[kx]) continue;
        float v = rp[ix[kx]];
        if (IN_RELU) v = fmaxf(v, 0.f);
        acc = fmaf(v, wp[ky * 4 + kx], acc);
      }
    }
  }
  if (OUT_RELU) acc = fmaxf(acc, 0.f);
  out[idx] = acc;                      // fp32 everywhere (incl. final recon)
}

// ---------------- VQ: argmin (first-min), zq in-place, idx (fp32) to d_out ----------------
__global__ __launch_bounds__(256) void k_vq(
    const float* __restrict__ z, const void* __restrict__ emb,
    float* __restrict__ zq, float* __restrict__ idx_out,
    const int* __restrict__ flag, float* __restrict__ lossp, int lossbase)
{
  __shared__ float sE[8192];
  __shared__ float sEE[128];
  __shared__ float wsum[4];
  int fl = flag[0];
  int tid = threadIdx.x;
  int n = blockIdx.x * 256 + tid;
  int nb = n >> 10, p = n & 1023;
  const float* zp = z + nb * 65536 + p;
  float zv[64];
  float zz = 0.f;
  #pragma unroll
  for (int d = 0; d < 64; ++d) { zv[d] = zp[d * 1024]; zz = fmaf(zv[d], zv[d], zz); }
  float best = 3.4e38f; int bidx = 0;
  for (int kb = 0; kb < 8; ++kb) {
    __syncthreads();
    for (int i = tid; i < 8192; i += 256) sE[i] = ldg_in(emb, kb * 8192 + i, fl);
    __syncthreads();
    if (tid < 128) {
      float s = 0.f;
      #pragma unroll
      for (int d = 0; d < 64; ++d) s = fmaf(sE[tid * 64 + d], sE[tid * 64 + d], s);
      sEE[tid] = s;
    }
    __syncthreads();
    for (int k = 0; k < 128; ++k) {
      const float* ep = sE + k * 64;
      float dot = 0.f;
      #pragma unroll
      for (int d = 0; d < 64; ++d) dot = fmaf(zv[d], ep[d], dot);
      float dist = zz + sEE[k] - 2.f * dot;
      if (dist < best) { best = dist; bidx = kb * 128 + k; }  // strict <: first min wins
    }
  }
  idx_out[n] = (float)bidx;
  float ls = 0.f;
  float* qp = zq + nb * 65536 + p;
  #pragma unroll
  for (int d = 0; d < 64; ++d) {
    float e = ldg_in(emb, bidx * 64 + d, fl);
    qp[d * 1024] = e;                  // in-place over z: thread owns its column
    float df = e - zv[d];
    ls = fmaf(df, df, ls);
  }
  #pragma unroll
  for (int off = 32; off > 0; off >>= 1) ls += __shfl_down(ls, off);
  if ((tid & 63) == 0) wsum[tid >> 6] = ls;
  __syncthreads();
  if (tid == 0) lossp[lossbase + blockIdx.x] = wsum[0] + wsum[1] + wsum[2] + wsum[3];
}

__global__ void k_loss_final(const float* __restrict__ lossp, float* __restrict__ out) {
  if (threadIdx.x == 0 && blockIdx.x == 0) {
    float s = 0.f;
    for (int i = 0; i < 256; ++i) s += lossp[i];
    float L = s * (1.f / 4194304.f);   // mean over 64*32*32*64
    out[R_RECON + 0] = L;              // codebook_loss
    out[R_RECON + 1] = L;              // commitment_loss (identical forward value)
  }
}

extern "C" void kernel_launch(void* const* d_in, const int* in_sizes, int n_in,
                              void* d_out, int out_size, void* d_ws, size_t ws_size,
                              hipStream_t stream)
{
  float* out = (float*)d_out;          // OUTPUT IS FP32 (validated by R8 ruler + R2..R9 signatures)

  // ws: F[0..256) loss partials | F[256] flag | arena at F[272..)
  float* F = (float*)d_ws;
  float* LOSSP = F;
  int* FLAG = (int*)(F + 256);
  float* A = F + 272;

  // per-chunk arena floats (overlapped liveness): Bc*393216
  //  H1=[0,Bc*262144)  H2=D1=[Bc*262144,Bc*393216)  H3=[0,Bc*131072)
  //  T=[Bc*131072,Bc*163840)  Z=[Bc*163840,Bc*229376)  D2=[0,Bc*262144)
  int Bc = 64;
  while (Bc > 1 && 4ull * (272ull + (size_t)Bc * 393216ull) > ws_size) Bc >>= 1;
  float* H1 = A;
  float* H2 = A + (size_t)Bc * 262144;
  float* H3 = A;
  float* T  = A + (size_t)Bc * 131072;
  float* Z  = A + (size_t)Bc * 163840;
  float* D1 = H2;
  float* D2 = A;

  const void* patch = d_in[0];
  const void* ew1 = d_in[1];  const void* eb1 = d_in[2];
  const void* ew2 = d_in[3];  const void* eb2 = d_in[4];
  const void* ew3 = d_in[5];  const void* eb3 = d_in[6];
  const void* er1a = d_in[7]; const void* er1b = d_in[8];
  const void* er2a = d_in[9]; const void* er2b = d_in[10];
  const void* pqw = d_in[11]; const void* pqb = d_in[12];
  const void* emb = d_in[13];
  const void* dw1 = d_in[14]; const void* db1 = d_in[15];
  const void* dr1a = d_in[16]; const void* dr1b = d_in[17];
  const void* dr2a = d_in[18]; const void* dr2b = d_in[19];
  const void* dw2 = d_in[20]; const void* db2 = d_in[21];
  const void* dw3 = d_in[22]; const void* db3 = d_in[23];

  k_detect<<<1, 256, 0, stream>>>((const u16*)patch, FLAG);

  int NC = 64 / Bc;
  for (int c = 0; c < NC; ++c) {
    int b0 = c * Bc;

    // ---- encoder ----
    k_conv_s2k4<true ><<<Bc * 1024, 256, 0, stream>>>(patch, ew1, eb1, H1, FLAG,
                                                      b0 * 49152, 3, 128, 64, 64);
    k_conv_s2k4<false><<<Bc * 512, 256, 0, stream>>>(H1, ew2, eb2, H2, FLAG,
                                                     0, 64, 64, 128, 32);
    k_conv3x3<false, false, false, true><<<Bc * 128, 256, 0, stream>>>(H2, ew3, eb3, H3, FLAG, 128, 128);
    k_conv3x3<true, false, true, false><<<Bc * 32, 256, 0, stream>>>(H3, er1a, nullptr, T, FLAG, 128, 32);
    k_conv1x1<false, true, false><<<Bc * 512, 256, 0, stream>>>(T, er1b, nullptr, H3, FLAG, 32, 128);
    k_conv3x3<true, false, true, false><<<Bc * 32, 256, 0, stream>>>(H3, er2a, nullptr, T, FLAG, 128, 32);
    k_conv1x1<false, true, false><<<Bc * 512, 256, 0, stream>>>(T, er2b, nullptr, H3, FLAG, 32, 128);
    k_conv1x1<true, false, true><<<Bc * 256, 256, 0, stream>>>(H3, pqw, pqb, Z, FLAG, 128, 64);

    // ---- VQ (zq in-place over Z; idx fp32 straight to d_out) ----
    k_vq<<<Bc * 4, 256, 0, stream>>>(Z, emb, Z, out + R_RECON + 2 + (size_t)b0 * 1024,
                                     FLAG, LOSSP, b0 * 4);

    // ---- decoder ----
    k_conv3x3<false, true, false, true><<<Bc * 128, 256, 0, stream>>>(Z, dw1, db1, D1, FLAG, 64, 128);
    k_conv3x3<true, false, true, false><<<Bc * 32, 256, 0, stream>>>(D1, dr1a, nullptr, T, FLAG, 128, 32);
    k_conv1x1<false, true, false><<<Bc * 512, 256, 0, stream>>>(T, dr1b, nullptr, D1, FLAG, 32, 128);
    k_conv3x3<true, false, true, false><<<Bc * 32, 256, 0, stream>>>(D1, dr2a, nullptr, T, FLAG, 128, 32);
    k_conv1x1<false, true, false><<<Bc * 512, 256, 0, stream>>>(T, dr2b, nullptr, D1, FLAG, 32, 128);
    k_convT_s2k4<true, true ><<<Bc * 1024, 256, 0, stream>>>(D1, dw2, db2, D2, FLAG, 128, 32, 64);
    k_convT_s2k4<false, false><<<Bc * 192, 256, 0, stream>>>(D2, dw3, db3,
                                      out + (size_t)b0 * 49152, FLAG, 64, 64, 3);
  }

  k_loss_final<<<1, 64, 0, stream>>>(LOSSP, out);
}